// Round 1
// 474.124 us; speedup vs baseline: 1.1139x; 1.1139x over previous
//
#include <hip/hip_runtime.h>

typedef __attribute__((ext_vector_type(8))) short short8;
typedef __attribute__((ext_vector_type(4))) float floatx4;
typedef __attribute__((ext_vector_type(16))) float floatx16;
typedef __attribute__((ext_vector_type(4))) unsigned int uintx4;

__device__ inline unsigned short f2bf(float f) {
    union { float f; unsigned int i; } c; c.f = f;
    unsigned int x = c.i;
    unsigned int r = x + 0x7fffu + ((x >> 16) & 1u);
    return (unsigned short)(r >> 16);
}

// pack two f32 -> two bf16 (RNE). NOTE: no clang builtin on gfx950 (m240) -> inline asm.
__device__ inline unsigned int pk_bf16(float lo, float hi) {
    unsigned int r;
    asm("v_cvt_pk_bf16_f32 %0, %1, %2" : "=v"(r) : "v"(lo), "v"(hi));
    return r;
}

// out0 = {a.lo-half, b.lo-half}, out1 = {a.hi-half, b.hi-half} (halves = lanes 0-31 / 32-63)
__device__ inline void plane_swap(unsigned int& a, unsigned int& b) {
#if __has_builtin(__builtin_amdgcn_permlane32_swap)
    auto r = __builtin_amdgcn_permlane32_swap(a, b, false, false);
    a = r[0]; b = r[1];
#else
    int lane = threadIdx.x & 63;
    unsigned int tb = (unsigned int)__shfl_xor((int)b, 32, 64);
    unsigned int ta = (unsigned int)__shfl_xor((int)a, 32, 64);
    unsigned int na = (lane < 32) ? a : tb;
    unsigned int nb = (lane < 32) ? ta : b;
    a = na; b = nb;
#endif
}

// async 16B global->LDS; lds base wave-uniform, lane l lands at base + l*16
__device__ inline void gl_lds16(const unsigned short* g, unsigned short* lds_uniform) {
    __builtin_amdgcn_global_load_lds(
        (const __attribute__((address_space(1))) void*)g,
        (__attribute__((address_space(3))) void*)lds_uniform,
        16, 0, 0);
}

// f32 -> bf16 elementwise, 8 elems/thread
__global__ void cvt_bf16(const float* __restrict__ in, unsigned short* __restrict__ out, int n8)
{
    int i = blockIdx.x * blockDim.x + threadIdx.x;
    if (i < n8) {
        const float4* p = (const float4*)(in + (size_t)i * 8);
        float4 a = p[0], b = p[1];
        short8 v;
        v[0] = (short)f2bf(a.x); v[1] = (short)f2bf(a.y);
        v[2] = (short)f2bf(a.z); v[3] = (short)f2bf(a.w);
        v[4] = (short)f2bf(b.x); v[5] = (short)f2bf(b.y);
        v[6] = (short)f2bf(b.z); v[7] = (short)f2bf(b.w);
        *(short8*)(out + (size_t)i * 8) = v;
    }
}

// pack mask int32 -> bits (16 ints -> u16)
__global__ void mask_pack(const int* __restrict__ m, unsigned short* __restrict__ o, int n16)
{
    int i = blockIdx.x * blockDim.x + threadIdx.x;
    if (i < n16) {
        const int4* p = (const int4*)(m + (size_t)i * 16);
        unsigned int bits = 0;
#pragma unroll
        for (int j = 0; j < 4; j++) {
            int4 v = p[j];
            bits |= (v.x != 0 ? 1u : 0u) << (j * 4 + 0);
            bits |= (v.y != 0 ? 1u : 0u) << (j * 4 + 1);
            bits |= (v.z != 0 ? 1u : 0u) << (j * 4 + 2);
            bits |= (v.w != 0 ? 1u : 0u) << (j * 4 + 3);
        }
        o[i] = (unsigned short)bits;
    }
}

// C = A[M,K] @ W[N,K]^T + bias[N]; A,W bf16; bias f32; MFMA bf16, acc fp32
// mode 0: out bf16 [b][h][s][d]; mode 1: out bf16 [b][h][d][s]; mode 2: out f32 [m][n]
__global__ __launch_bounds__(256, 2)
void gemm_bt(const unsigned short* __restrict__ A,
             const unsigned short* __restrict__ W,
             const float* __restrict__ bias,
             void* __restrict__ outv,
             int M, int N, int K, int mode)
{
    __shared__ __align__(16) unsigned short As[128 * 64]; // LDS[row][slot]=glob[row][slot^(row&7)]
    __shared__ __align__(16) unsigned short Bs[128 * 64];
    const int t = threadIdx.x, lane = t & 63, wv = t >> 6;
    const int quad = lane >> 4, l16 = lane & 15;
    const int m0 = blockIdx.x * 128, n0 = blockIdx.y * 128;
    const int wm = (wv >> 1) * 64, wn = (wv & 1) * 64;

    floatx4 acc[4][4] = {};

    for (int k0 = 0; k0 < K; k0 += 64) {
#pragma unroll
        for (int s = 0; s < 4; s++) {
            int e = t + s * 256;
            int row = e >> 3, slot = e & 7;
            int chunk = slot ^ (row & 7);
            gl_lds16(&A[(size_t)(m0 + row) * K + k0 + chunk * 8], &As[wv * 512 + s * 2048]);
            gl_lds16(&W[(size_t)(n0 + row) * K + k0 + chunk * 8], &Bs[wv * 512 + s * 2048]);
        }
        asm volatile("s_waitcnt vmcnt(0)" ::: "memory");
        __syncthreads();

        short8 af[4][2], bfr[4][2];
#pragma unroll
        for (int i = 0; i < 4; i++)
#pragma unroll
            for (int c = 0; c < 2; c++)
                af[i][c] = *(const short8*)&As[(wm + i * 16 + l16) * 64 + (((c * 4 + quad) ^ (l16 & 7)) * 8)];
#pragma unroll
        for (int j = 0; j < 4; j++)
#pragma unroll
            for (int c = 0; c < 2; c++)
                bfr[j][c] = *(const short8*)&Bs[(wn + j * 16 + l16) * 64 + (((c * 4 + quad) ^ (l16 & 7)) * 8)];

#pragma unroll
        for (int c = 0; c < 2; c++)
#pragma unroll
            for (int i = 0; i < 4; i++)
#pragma unroll
                for (int j = 0; j < 4; j++)
                    acc[i][j] = __builtin_amdgcn_mfma_f32_16x16x32_bf16(af[i][c], bfr[j][c], acc[i][j], 0, 0, 0);
        __syncthreads();
    }

    // C/D layout: col=lane&15, row=quad*4+reg
#pragma unroll
    for (int i = 0; i < 4; i++) {
#pragma unroll
        for (int j = 0; j < 4; j++) {
            int n = n0 + wn + j * 16 + l16;
            float bv = bias[n];
#pragma unroll
            for (int r = 0; r < 4; r++) {
                int m = m0 + wm + i * 16 + quad * 4 + r;
                float v = acc[i][j][r] + bv;
                if (mode == 2) {
                    ((float*)outv)[(size_t)m * N + n] = v;
                } else {
                    int b = m >> 11, s = m & 2047, h = n >> 6, d = n & 63;
                    size_t idx = (mode == 0)
                        ? (((size_t)b * 16 + h) * 2048 + s) * 64 + d
                        : (((size_t)b * 16 + h) * 64 + d) * 2048 + s;
                    ((unsigned short*)outv)[idx] = f2bf(v);
                }
            }
        }
    }
}

// flash attention, static-max softmax, swapped QK^T (S^T = K·Q^T via 32x32x16 MFMA):
// lane owns one q-row (col = lane&31), 16 keys/lane (lane<32 / lane>=32 split rows).
// Softmax fully in-register; P re-layout to PV B-frag via v_cvt_pk_bf16_f32 + permlane32_swap.
// PV computes O^T[d][q] = V^T · P^T.  K/V LDS double-buffered; one barrier per k-tile.
// 1D grid: bh = blockIdx.x & 63 (XCD-local), qtile = blockIdx.x >> 6; 4 waves * 32 q-rows.
__global__ __launch_bounds__(256, 4)
void attn(const unsigned short* __restrict__ qb,
          const unsigned short* __restrict__ kb,
          const unsigned short* __restrict__ vtb,
          const unsigned char* __restrict__ mb,
          unsigned short* __restrict__ ob)
{
    __shared__ __align__(16) unsigned short Ks[2][64 * 64]; // [key][d] swizzled
    __shared__ __align__(16) unsigned short Vs[2][64 * 64]; // [d][key] swizzled
    const int t = threadIdx.x, lane = t & 63, wv = t >> 6;
    const int hi = lane >> 5, l31 = lane & 31;
    const int bh = blockIdx.x & 63;           // same bh -> same XCD (mod-8 invariant)
    const int b = bh >> 4, h = bh & 15;
    const int q0 = (blockIdx.x >> 6) * 128;
    const size_t kvbase = (size_t)bh * 2048 * 64;
    // p = exp(s/8 - 10) = exp2(s*0.125*log2e - 10*log2e)
    const float K1 = 0.1803368801f;           // 0.125 * log2(e)
    const float K2 = -14.4269504089f;         // -10 * log2(e)
    const float PM = 4.5399931e-05f;          // exp(1e-11 - 10)

    const int qr = q0 + wv * 32 + l31;        // this lane's q-row

    // Q as B-fragment: qf[g] = Q[q=l31][d = g*16 + hi*8 + j], j=0..7
    short8 qf[4];
#pragma unroll
    for (int g = 0; g < 4; g++)
        qf[g] = *(const short8*)&qb[kvbase + (size_t)qr * 64 + g * 16 + hi * 8];

    const uint2* mrowp = (const uint2*)(mb + ((size_t)b * 2048 + qr) * 256);
    uint2 mcur = mrowp[0];

    floatx16 O[2] = {};   // O^T tiles (dtile 0: d 0..31, dtile 1: d 32..63); C layout col=q
    float lrun = 0.f;

    // prologue: stage tile 0 into buffer 0
#pragma unroll
    for (int s = 0; s < 2; s++) {
        int e = t + s * 256;
        int row = e >> 3, slot = e & 7, chunk = slot ^ (row & 7);
        gl_lds16(&kb[kvbase + (size_t)row * 64 + chunk * 8], &Ks[0][wv * 512 + s * 2048]);
        gl_lds16(&vtb[kvbase + (size_t)row * 2048 + chunk * 8], &Vs[0][wv * 512 + s * 2048]);
    }

    for (int kt = 0; kt < 2048; kt += 64) {
        const int cur = (kt >> 6) & 1;
        asm volatile("s_waitcnt vmcnt(0)" ::: "memory"); // my stage loads for cur landed
        __syncthreads();                                 // everyone's landed; prev reads done

        // issue next tile's stage + mask load; they fly across this tile's compute
        uint2 mnext = mcur;
        if (kt + 64 < 2048) {
#pragma unroll
            for (int s = 0; s < 2; s++) {
                int e = t + s * 256;
                int row = e >> 3, slot = e & 7, chunk = slot ^ (row & 7);
                gl_lds16(&kb[kvbase + (size_t)(kt + 64 + row) * 64 + chunk * 8],
                         &Ks[cur ^ 1][wv * 512 + s * 2048]);
                gl_lds16(&vtb[kvbase + (size_t)row * 2048 + (kt + 64) + chunk * 8],
                         &Vs[cur ^ 1][wv * 512 + s * 2048]);
            }
            mnext = mrowp[(kt >> 6) + 1];
        }

#pragma unroll
        for (int c32 = 0; c32 < 2; c32++) {
            // K as A-fragment: rows c32*32 + l31 of the 64-key tile
            const int krow = c32 * 32 + l31;
            short8 kf[4];
#pragma unroll
            for (int g = 0; g < 4; g++)
                kf[g] = *(const short8*)&Ks[cur][krow * 64 + (((g * 2 + hi) ^ (krow & 7)) * 8)];

            floatx16 C = {};   // S^T: C[row=key][col=q]
#pragma unroll
            for (int g = 0; g < 4; g++)
                C = __builtin_amdgcn_mfma_f32_32x32x16_bf16(kf[g], qf[g], C, 0, 0, 0);

            // softmax (static max), mask select; key(r) = (r&3) + 8*(r>>2) + 4*hi
            unsigned int w = (c32 ? mcur.y : mcur.x) >> (hi * 4);
            float p[16];
            float rs = 0.f;
#pragma unroll
            for (int r = 0; r < 16; r++) {
                float e_ = exp2f(fmaf(C[r], K1, K2));
                unsigned int bit = (w >> ((r & 3) + 8 * (r >> 2))) & 1u;
                p[r] = bit ? e_ : PM;
                rs += p[r];
            }
            lrun += rs;

            // P -> bf16 PV B-frags: 8 cvt_pk + 4 permlane32_swap
            unsigned int s_[8];
#pragma unroll
            for (int i = 0; i < 8; i++) s_[i] = pk_bf16(p[2 * i], p[2 * i + 1]);
            plane_swap(s_[0], s_[2]); plane_swap(s_[1], s_[3]);
            plane_swap(s_[4], s_[6]); plane_swap(s_[5], s_[7]);
            short8 fragA = __builtin_bit_cast(short8, (uintx4){s_[0], s_[1], s_[2], s_[3]}); // keys c32*32+0..15
            short8 fragB = __builtin_bit_cast(short8, (uintx4){s_[4], s_[5], s_[6], s_[7]}); // keys c32*32+16..31

            // O^T[dtile] += V^T-frag · P-frag
#pragma unroll
            for (int dt = 0; dt < 2; dt++) {
                const int vrow = dt * 32 + l31;
                short8 vA = *(const short8*)&Vs[cur][vrow * 64 + (((c32 * 4 + hi) ^ (vrow & 7)) * 8)];
                short8 vB = *(const short8*)&Vs[cur][vrow * 64 + (((c32 * 4 + 2 + hi) ^ (vrow & 7)) * 8)];
                O[dt] = __builtin_amdgcn_mfma_f32_32x32x16_bf16(vA, fragA, O[dt], 0, 0, 0);
                O[dt] = __builtin_amdgcn_mfma_f32_32x32x16_bf16(vB, fragB, O[dt], 0, 0, 0);
            }
        }
        mcur = mnext;
        __syncthreads(); // all reads of cur done before next iter overwrites cur^1... (cheap; keeps write-after-read safe for last wave)
    }

    // epilogue: combine the two key-half partial sums (same q in lane and lane^32)
    float l = lrun + __shfl_xor(lrun, 32, 64);
    float inv = 1.0f / l;
#pragma unroll
    for (int dt = 0; dt < 2; dt++)
#pragma unroll
        for (int g = 0; g < 4; g++) {
            int d0 = dt * 32 + 8 * g + 4 * hi;          // rows d = d0..d0+3 for regs 4g..4g+3
            unsigned int w0 = pk_bf16(O[dt][4 * g + 0] * inv, O[dt][4 * g + 1] * inv);
            unsigned int w1 = pk_bf16(O[dt][4 * g + 2] * inv, O[dt][4 * g + 3] * inv);
            uint2 ww; ww.x = w0; ww.y = w1;
            *(uint2*)&ob[((size_t)b * 2048 + qr) * 1024 + h * 64 + d0] = ww;
        }
}

extern "C" void kernel_launch(void* const* d_in, const int* in_sizes, int n_in,
                              void* d_out, int out_size, void* d_ws, size_t ws_size,
                              hipStream_t stream)
{
    const float* query = (const float*)d_in[0];
    const float* key   = (const float*)d_in[1];
    const float* value = (const float*)d_in[2];
    const int*   mask  = (const int*)d_in[3];
    const float* wq = (const float*)d_in[4];
    const float* bq = (const float*)d_in[5];
    const float* wk = (const float*)d_in[6];
    const float* bk = (const float*)d_in[7];
    const float* wv = (const float*)d_in[8];
    const float* bv = (const float*)d_in[9];
    const float* wo = (const float*)d_in[10];
    const float* bo = (const float*)d_in[11];

    // ws (48 MB): S0 | S1 | S2, 16 MB each.
    // d_out (32 MB f32): D0 = vtb bf16 [0,16), D1 = weight-bf16 / packed-mask [16,18).
    char* ws = (char*)d_ws;
    const size_t T = 16777216;
    unsigned short* S0 = (unsigned short*)(ws);
    unsigned short* S1 = (unsigned short*)(ws + T);
    unsigned short* S2 = (unsigned short*)(ws + 2 * T);
    unsigned short* D0 = (unsigned short*)d_out;
    unsigned short* D1 = (unsigned short*)((char*)d_out + T);

    dim3 g(64, 8); // M/128, N/128

    // Q = query @ wq^T + bq
    cvt_bf16<<<dim3(4096), 256, 0, stream>>>(query, S0, 1048576);
    cvt_bf16<<<dim3(512),  256, 0, stream>>>(wq, D1, 131072);
    gemm_bt<<<g, 256, 0, stream>>>(S0, D1, bq, S1, 8192, 1024, 1024, 0);
    // K
    cvt_bf16<<<dim3(4096), 256, 0, stream>>>(key, S0, 1048576);
    cvt_bf16<<<dim3(512),  256, 0, stream>>>(wk, D1, 131072);
    gemm_bt<<<g, 256, 0, stream>>>(S0, D1, bk, S2, 8192, 1024, 1024, 0);
    // V (transposed layout)
    cvt_bf16<<<dim3(4096), 256, 0, stream>>>(value, S0, 1048576);
    cvt_bf16<<<dim3(512),  256, 0, stream>>>(wv, D1, 131072);
    gemm_bt<<<g, 256, 0, stream>>>(S0, D1, bv, D0, 8192, 1024, 1024, 1);

    mask_pack<<<dim3(4096), 256, 0, stream>>>(mask, D1, 1048576);

    attn<<<dim3(1024), 256, 0, stream>>>(S1, S2, D0, (const unsigned char*)D1, S0);

    // out = ob @ wo^T + bo  (f32 output)
    cvt_bf16<<<dim3(512), 256, 0, stream>>>(wo, S1, 131072);
    gemm_bt<<<g, 256, 0, stream>>>(S0, S1, bo, d_out, 8192, 1024, 1024, 2);
}

// Round 4
// 470.705 us; speedup vs baseline: 1.1220x; 1.0073x over previous
//
#include <hip/hip_runtime.h>

typedef __attribute__((ext_vector_type(8))) short short8;
typedef __attribute__((ext_vector_type(4))) float floatx4;
typedef __attribute__((ext_vector_type(16))) float floatx16;
typedef __attribute__((ext_vector_type(4))) unsigned int uintx4;

__device__ inline unsigned short f2bf(float f) {
    union { float f; unsigned int i; } c; c.f = f;
    unsigned int x = c.i;
    unsigned int r = x + 0x7fffu + ((x >> 16) & 1u);
    return (unsigned short)(r >> 16);
}

// pack two f32 -> two bf16 (RNE). NOTE: no clang builtin on gfx950 (m240) -> inline asm.
__device__ inline unsigned int pk_bf16(float lo, float hi) {
    unsigned int r;
    asm("v_cvt_pk_bf16_f32 %0, %1, %2" : "=v"(r) : "v"(lo), "v"(hi));
    return r;
}

// out0 = {a.lo-half, b.lo-half}, out1 = {a.hi-half, b.hi-half} (halves = lanes 0-31 / 32-63)
__device__ inline void plane_swap(unsigned int& a, unsigned int& b) {
#if __has_builtin(__builtin_amdgcn_permlane32_swap)
    auto r = __builtin_amdgcn_permlane32_swap(a, b, false, false);
    a = r[0]; b = r[1];
#else
    int lane = threadIdx.x & 63;
    unsigned int tb = (unsigned int)__shfl_xor((int)b, 32, 64);
    unsigned int ta = (unsigned int)__shfl_xor((int)a, 32, 64);
    unsigned int na = (lane < 32) ? a : tb;
    unsigned int nb = (lane < 32) ? ta : b;
    a = na; b = nb;
#endif
}

// async 16B global->LDS; lds base wave-uniform, lane l lands at base + l*16
__device__ inline void gl_lds16(const unsigned short* g, unsigned short* lds_uniform) {
    __builtin_amdgcn_global_load_lds(
        (const __attribute__((address_space(1))) void*)g,
        (__attribute__((address_space(3))) void*)lds_uniform,
        16, 0, 0);
}

// f32 -> bf16 elementwise, 8 elems/thread
__global__ void cvt_bf16(const float* __restrict__ in, unsigned short* __restrict__ out, int n8)
{
    int i = blockIdx.x * blockDim.x + threadIdx.x;
    if (i < n8) {
        const float4* p = (const float4*)(in + (size_t)i * 8);
        float4 a = p[0], b = p[1];
        short8 v;
        v[0] = (short)f2bf(a.x); v[1] = (short)f2bf(a.y);
        v[2] = (short)f2bf(a.z); v[3] = (short)f2bf(a.w);
        v[4] = (short)f2bf(b.x); v[5] = (short)f2bf(b.y);
        v[6] = (short)f2bf(b.z); v[7] = (short)f2bf(b.w);
        *(short8*)(out + (size_t)i * 8) = v;
    }
}

// 3 weight matrices in one launch (blockIdx.y selects)
__global__ void cvt_bf16_3(const float* __restrict__ i0, const float* __restrict__ i1,
                           const float* __restrict__ i2,
                           unsigned short* __restrict__ o0, unsigned short* __restrict__ o1,
                           unsigned short* __restrict__ o2, int n8)
{
    const int w = blockIdx.y;
    const float* in = (w == 0) ? i0 : (w == 1) ? i1 : i2;
    unsigned short* out = (w == 0) ? o0 : (w == 1) ? o1 : o2;
    int i = blockIdx.x * blockDim.x + threadIdx.x;
    if (i < n8) {
        const float4* p = (const float4*)(in + (size_t)i * 8);
        float4 a = p[0], b = p[1];
        short8 v;
        v[0] = (short)f2bf(a.x); v[1] = (short)f2bf(a.y);
        v[2] = (short)f2bf(a.z); v[3] = (short)f2bf(a.w);
        v[4] = (short)f2bf(b.x); v[5] = (short)f2bf(b.y);
        v[6] = (short)f2bf(b.z); v[7] = (short)f2bf(b.w);
        *(short8*)(out + (size_t)i * 8) = v;
    }
}

// pack mask int32 -> bits (16 ints -> u16)
__global__ void mask_pack(const int* __restrict__ m, unsigned short* __restrict__ o, int n16)
{
    int i = blockIdx.x * blockDim.x + threadIdx.x;
    if (i < n16) {
        const int4* p = (const int4*)(m + (size_t)i * 16);
        unsigned int bits = 0;
#pragma unroll
        for (int j = 0; j < 4; j++) {
            int4 v = p[j];
            bits |= (v.x != 0 ? 1u : 0u) << (j * 4 + 0);
            bits |= (v.y != 0 ? 1u : 0u) << (j * 4 + 1);
            bits |= (v.z != 0 ? 1u : 0u) << (j * 4 + 2);
            bits |= (v.w != 0 ? 1u : 0u) << (j * 4 + 3);
        }
        o[i] = (unsigned short)bits;
    }
}

// C = A[M,K] @ W[N,K]^T + bias[N]; A,W bf16; bias f32; MFMA bf16, acc fp32
// mode 0: out bf16 [b][h][s][d]; mode 1: out bf16 [b][h][d][s]; mode 2: out f32 [m][n]
__global__ __launch_bounds__(256, 2)
void gemm_bt(const unsigned short* __restrict__ A,
             const unsigned short* __restrict__ W,
             const float* __restrict__ bias,
             void* __restrict__ outv,
             int M, int N, int K, int mode)
{
    __shared__ __align__(16) unsigned short As[128 * 64]; // LDS[row][slot]=glob[row][slot^(row&7)]
    __shared__ __align__(16) unsigned short Bs[128 * 64];
    const int t = threadIdx.x, lane = t & 63, wv = t >> 6;
    const int quad = lane >> 4, l16 = lane & 15;
    const int m0 = blockIdx.x * 128, n0 = blockIdx.y * 128;
    const int wm = (wv >> 1) * 64, wn = (wv & 1) * 64;

    floatx4 acc[4][4] = {};

    for (int k0 = 0; k0 < K; k0 += 64) {
#pragma unroll
        for (int s = 0; s < 4; s++) {
            int e = t + s * 256;
            int row = e >> 3, slot = e & 7;
            int chunk = slot ^ (row & 7);
            gl_lds16(&A[(size_t)(m0 + row) * K + k0 + chunk * 8], &As[wv * 512 + s * 2048]);
            gl_lds16(&W[(size_t)(n0 + row) * K + k0 + chunk * 8], &Bs[wv * 512 + s * 2048]);
        }
        asm volatile("s_waitcnt vmcnt(0)" ::: "memory");
        __syncthreads();

        short8 af[4][2], bfr[4][2];
#pragma unroll
        for (int i = 0; i < 4; i++)
#pragma unroll
            for (int c = 0; c < 2; c++)
                af[i][c] = *(const short8*)&As[(wm + i * 16 + l16) * 64 + (((c * 4 + quad) ^ (l16 & 7)) * 8)];
#pragma unroll
        for (int j = 0; j < 4; j++)
#pragma unroll
            for (int c = 0; c < 2; c++)
                bfr[j][c] = *(const short8*)&Bs[(wn + j * 16 + l16) * 64 + (((c * 4 + quad) ^ (l16 & 7)) * 8)];

#pragma unroll
        for (int c = 0; c < 2; c++)
#pragma unroll
            for (int i = 0; i < 4; i++)
#pragma unroll
                for (int j = 0; j < 4; j++)
                    acc[i][j] = __builtin_amdgcn_mfma_f32_16x16x32_bf16(af[i][c], bfr[j][c], acc[i][j], 0, 0, 0);
        __syncthreads();
    }

    // C/D layout: col=lane&15, row=quad*4+reg
#pragma unroll
    for (int i = 0; i < 4; i++) {
#pragma unroll
        for (int j = 0; j < 4; j++) {
            int n = n0 + wn + j * 16 + l16;
            float bv = bias[n];
#pragma unroll
            for (int r = 0; r < 4; r++) {
                int m = m0 + wm + i * 16 + quad * 4 + r;
                float v = acc[i][j][r] + bv;
                if (mode == 2) {
                    ((float*)outv)[(size_t)m * N + n] = v;
                } else {
                    int b = m >> 11, s = m & 2047, h = n >> 6, d = n & 63;
                    size_t idx = (mode == 0)
                        ? (((size_t)b * 16 + h) * 2048 + s) * 64 + d
                        : (((size_t)b * 16 + h) * 64 + d) * 2048 + s;
                    ((unsigned short*)outv)[idx] = f2bf(v);
                }
            }
        }
    }
}

// flash attention — BISECT ROUND: attn kernel reverted byte-for-byte to the ROUND-1
// version that PASSED (post-exp mask select, exp2f, f32 lrun + epilogue shfl, no Osum).
// Only the launcher (cvt_bf16_3 + separate WQ/WK/WV/MB regions) is kept from R2/R3.
// If this passes -> the ones-MFMA denominator block was the R2/R3 bug.
// If this fails -> the launcher/buffer layout is the bug.
__global__ __launch_bounds__(256, 4)
void attn(const unsigned short* __restrict__ qb,
          const unsigned short* __restrict__ kb,
          const unsigned short* __restrict__ vtb,
          const unsigned char* __restrict__ mb,
          unsigned short* __restrict__ ob)
{
    __shared__ __align__(16) unsigned short Ks[2][64 * 64]; // [key][d] swizzled
    __shared__ __align__(16) unsigned short Vs[2][64 * 64]; // [d][key] swizzled
    const int t = threadIdx.x, lane = t & 63, wv = t >> 6;
    const int hi = lane >> 5, l31 = lane & 31;
    const int bh = blockIdx.x & 63;           // same bh -> same XCD (mod-8 invariant)
    const int b = bh >> 4, h = bh & 15;
    const int q0 = (blockIdx.x >> 6) * 128;
    const size_t kvbase = (size_t)bh * 2048 * 64;
    // p = exp(s/8 - 10) = exp2(s*0.125*log2e - 10*log2e)
    const float K1 = 0.1803368801f;           // 0.125 * log2(e)
    const float K2 = -14.4269504089f;         // -10 * log2(e)
    const float PM = 4.5399931e-05f;          // exp(1e-11 - 10)

    const int qr = q0 + wv * 32 + l31;        // this lane's q-row

    // Q as B-fragment: qf[g] = Q[q=l31][d = g*16 + hi*8 + j], j=0..7
    short8 qf[4];
#pragma unroll
    for (int g = 0; g < 4; g++)
        qf[g] = *(const short8*)&qb[kvbase + (size_t)qr * 64 + g * 16 + hi * 8];

    const uint2* mrowp = (const uint2*)(mb + ((size_t)b * 2048 + qr) * 256);
    uint2 mcur = mrowp[0];

    floatx16 O[2] = {};   // O^T tiles (dtile 0: d 0..31, dtile 1: d 32..63); C layout col=q
    float lrun = 0.f;

    // prologue: stage tile 0 into buffer 0
#pragma unroll
    for (int s = 0; s < 2; s++) {
        int e = t + s * 256;
        int row = e >> 3, slot = e & 7, chunk = slot ^ (row & 7);
        gl_lds16(&kb[kvbase + (size_t)row * 64 + chunk * 8], &Ks[0][wv * 512 + s * 2048]);
        gl_lds16(&vtb[kvbase + (size_t)row * 2048 + chunk * 8], &Vs[0][wv * 512 + s * 2048]);
    }

    for (int kt = 0; kt < 2048; kt += 64) {
        const int cur = (kt >> 6) & 1;
        asm volatile("s_waitcnt vmcnt(0)" ::: "memory"); // my stage loads for cur landed
        __syncthreads();                                 // everyone's landed; prev reads done

        // issue next tile's stage + mask load; they fly across this tile's compute
        uint2 mnext = mcur;
        if (kt + 64 < 2048) {
#pragma unroll
            for (int s = 0; s < 2; s++) {
                int e = t + s * 256;
                int row = e >> 3, slot = e & 7, chunk = slot ^ (row & 7);
                gl_lds16(&kb[kvbase + (size_t)(kt + 64 + row) * 64 + chunk * 8],
                         &Ks[cur ^ 1][wv * 512 + s * 2048]);
                gl_lds16(&vtb[kvbase + (size_t)row * 2048 + (kt + 64) + chunk * 8],
                         &Vs[cur ^ 1][wv * 512 + s * 2048]);
            }
            mnext = mrowp[(kt >> 6) + 1];
        }

#pragma unroll
        for (int c32 = 0; c32 < 2; c32++) {
            // K as A-fragment: rows c32*32 + l31 of the 64-key tile
            const int krow = c32 * 32 + l31;
            short8 kf[4];
#pragma unroll
            for (int g = 0; g < 4; g++)
                kf[g] = *(const short8*)&Ks[cur][krow * 64 + (((g * 2 + hi) ^ (krow & 7)) * 8)];

            floatx16 C = {};   // S^T: C[row=key][col=q]
#pragma unroll
            for (int g = 0; g < 4; g++)
                C = __builtin_amdgcn_mfma_f32_32x32x16_bf16(kf[g], qf[g], C, 0, 0, 0);

            // softmax (static max), mask select; key(r) = (r&3) + 8*(r>>2) + 4*hi
            unsigned int w = (c32 ? mcur.y : mcur.x) >> (hi * 4);
            float p[16];
            float rs = 0.f;
#pragma unroll
            for (int r = 0; r < 16; r++) {
                float e_ = exp2f(fmaf(C[r], K1, K2));
                unsigned int bit = (w >> ((r & 3) + 8 * (r >> 2))) & 1u;
                p[r] = bit ? e_ : PM;
                rs += p[r];
            }
            lrun += rs;

            // P -> bf16 PV B-frags: 8 cvt_pk + 4 permlane32_swap
            unsigned int s_[8];
#pragma unroll
            for (int i = 0; i < 8; i++) s_[i] = pk_bf16(p[2 * i], p[2 * i + 1]);
            plane_swap(s_[0], s_[2]); plane_swap(s_[1], s_[3]);
            plane_swap(s_[4], s_[6]); plane_swap(s_[5], s_[7]);
            short8 fragA = __builtin_bit_cast(short8, (uintx4){s_[0], s_[1], s_[2], s_[3]}); // keys c32*32+0..15
            short8 fragB = __builtin_bit_cast(short8, (uintx4){s_[4], s_[5], s_[6], s_[7]}); // keys c32*32+16..31

            // O^T[dtile] += V^T-frag · P-frag
#pragma unroll
            for (int dt = 0; dt < 2; dt++) {
                const int vrow = dt * 32 + l31;
                short8 vA = *(const short8*)&Vs[cur][vrow * 64 + (((c32 * 4 + hi) ^ (vrow & 7)) * 8)];
                short8 vB = *(const short8*)&Vs[cur][vrow * 64 + (((c32 * 4 + 2 + hi) ^ (vrow & 7)) * 8)];
                O[dt] = __builtin_amdgcn_mfma_f32_32x32x16_bf16(vA, fragA, O[dt], 0, 0, 0);
                O[dt] = __builtin_amdgcn_mfma_f32_32x32x16_bf16(vB, fragB, O[dt], 0, 0, 0);
            }
        }
        mcur = mnext;
        __syncthreads(); // all reads of cur done before next iter overwrites cur^1
    }

    // epilogue: combine the two key-half partial sums (same q in lane and lane^32)
    float l = lrun + __shfl_xor(lrun, 32, 64);
    float inv = 1.0f / l;
#pragma unroll
    for (int dt = 0; dt < 2; dt++)
#pragma unroll
        for (int g = 0; g < 4; g++) {
            int d0 = dt * 32 + 8 * g + 4 * hi;          // rows d = d0..d0+3 for regs 4g..4g+3
            unsigned int w0 = pk_bf16(O[dt][4 * g + 0] * inv, O[dt][4 * g + 1] * inv);
            unsigned int w1 = pk_bf16(O[dt][4 * g + 2] * inv, O[dt][4 * g + 3] * inv);
            uint2 ww; ww.x = w0; ww.y = w1;
            *(uint2*)&ob[((size_t)b * 2048 + qr) * 1024 + h * 64 + d0] = ww;
        }
}

extern "C" void kernel_launch(void* const* d_in, const int* in_sizes, int n_in,
                              void* d_out, int out_size, void* d_ws, size_t ws_size,
                              hipStream_t stream)
{
    const float* query = (const float*)d_in[0];
    const float* key   = (const float*)d_in[1];
    const float* value = (const float*)d_in[2];
    const int*   mask  = (const int*)d_in[3];
    const float* wq = (const float*)d_in[4];
    const float* bq = (const float*)d_in[5];
    const float* wk = (const float*)d_in[6];
    const float* bk = (const float*)d_in[7];
    const float* wv = (const float*)d_in[8];
    const float* bv = (const float*)d_in[9];
    const float* wo = (const float*)d_in[10];
    const float* bo = (const float*)d_in[11];

    // ws (48 MB): S0 | S1 | S2, 16 MB each.
    // d_out (32 MB f32): D0 = vtb bf16 [0,16) | WQ [16,18) | WK [18,20) | WV [20,22) | MB mask [22,24).
    // All d_out scratch is dead before the final gemm overwrites d_out with f32 output.
    // wo cannot live in d_out (final gemm reads it while writing d_out) -> S1 post-attn.
    char* ws = (char*)d_ws;
    const size_t T = 16777216;
    unsigned short* S0 = (unsigned short*)(ws);
    unsigned short* S1 = (unsigned short*)(ws + T);
    unsigned short* S2 = (unsigned short*)(ws + 2 * T);
    unsigned short* D0 = (unsigned short*)d_out;
    unsigned short* WQ = (unsigned short*)((char*)d_out + T);
    unsigned short* WK = (unsigned short*)((char*)d_out + T + 2097152);
    unsigned short* WV = (unsigned short*)((char*)d_out + T + 2 * 2097152);
    unsigned short* MB = (unsigned short*)((char*)d_out + T + 3 * 2097152);

    dim3 g(64, 8); // M/128, N/128

    // weights (q,k,v) in one launch; mask pack
    cvt_bf16_3<<<dim3(512, 3), 256, 0, stream>>>(wq, wk, wv, WQ, WK, WV, 131072);
    mask_pack<<<dim3(4096), 256, 0, stream>>>(mask, MB, 1048576);

    // Q = query @ wq^T + bq
    cvt_bf16<<<dim3(4096), 256, 0, stream>>>(query, S0, 1048576);
    gemm_bt<<<g, 256, 0, stream>>>(S0, WQ, bq, S1, 8192, 1024, 1024, 0);
    // K
    cvt_bf16<<<dim3(4096), 256, 0, stream>>>(key, S0, 1048576);
    gemm_bt<<<g, 256, 0, stream>>>(S0, WK, bk, S2, 8192, 1024, 1024, 0);
    // V (transposed layout)
    cvt_bf16<<<dim3(4096), 256, 0, stream>>>(value, S0, 1048576);
    gemm_bt<<<g, 256, 0, stream>>>(S0, WV, bv, D0, 8192, 1024, 1024, 1);

    attn<<<dim3(1024), 256, 0, stream>>>(S1, S2, D0, (const unsigned char*)MB, S0);

    // out = ob @ wo^T + bo  (f32 output)
    cvt_bf16<<<dim3(512), 256, 0, stream>>>(wo, S1, 131072);
    gemm_bt<<<g, 256, 0, stream>>>(S0, S1, bo, d_out, 8192, 1024, 1024, 2);
}

// Round 6
// 426.183 us; speedup vs baseline: 1.2392x; 1.1045x over previous
//
#include <hip/hip_runtime.h>

typedef __attribute__((ext_vector_type(8))) short short8;
typedef __attribute__((ext_vector_type(4))) float floatx4;
typedef __attribute__((ext_vector_type(16))) float floatx16;
typedef __attribute__((ext_vector_type(4))) unsigned int uintx4;

__device__ inline unsigned short f2bf(float f) {
    union { float f; unsigned int i; } c; c.f = f;
    unsigned int x = c.i;
    unsigned int r = x + 0x7fffu + ((x >> 16) & 1u);
    return (unsigned short)(r >> 16);
}

// pack two f32 -> two bf16 (RNE). NOTE: no clang builtin on gfx950 (m240) -> inline asm.
__device__ inline unsigned int pk_bf16(float lo, float hi) {
    unsigned int r;
    asm("v_cvt_pk_bf16_f32 %0, %1, %2" : "=v"(r) : "v"(lo), "v"(hi));
    return r;
}

// R5 SINGLE DELTA: raw hardware 2^x. Inputs here are in [-25,-7]; no range handling
// needed, so skip the OCML safe wrapper. Guarded: fallback == R4 behavior exactly.
__device__ inline float ex2(float x) {
#if __has_builtin(__builtin_amdgcn_exp2f)
    return __builtin_amdgcn_exp2f(x);
#else
    return exp2f(x);
#endif
}

// out0 = {a.lo-half, b.lo-half}, out1 = {a.hi-half, b.hi-half} (halves = lanes 0-31 / 32-63)
__device__ inline void plane_swap(unsigned int& a, unsigned int& b) {
#if __has_builtin(__builtin_amdgcn_permlane32_swap)
    auto r = __builtin_amdgcn_permlane32_swap(a, b, false, false);
    a = r[0]; b = r[1];
#else
    int lane = threadIdx.x & 63;
    unsigned int tb = (unsigned int)__shfl_xor((int)b, 32, 64);
    unsigned int ta = (unsigned int)__shfl_xor((int)a, 32, 64);
    unsigned int na = (lane < 32) ? a : tb;
    unsigned int nb = (lane < 32) ? ta : b;
    a = na; b = nb;
#endif
}

// async 16B global->LDS; lds base wave-uniform, lane l lands at base + l*16
__device__ inline void gl_lds16(const unsigned short* g, unsigned short* lds_uniform) {
    __builtin_amdgcn_global_load_lds(
        (const __attribute__((address_space(1))) void*)g,
        (__attribute__((address_space(3))) void*)lds_uniform,
        16, 0, 0);
}

// f32 -> bf16 elementwise, 8 elems/thread
__global__ void cvt_bf16(const float* __restrict__ in, unsigned short* __restrict__ out, int n8)
{
    int i = blockIdx.x * blockDim.x + threadIdx.x;
    if (i < n8) {
        const float4* p = (const float4*)(in + (size_t)i * 8);
        float4 a = p[0], b = p[1];
        short8 v;
        v[0] = (short)f2bf(a.x); v[1] = (short)f2bf(a.y);
        v[2] = (short)f2bf(a.z); v[3] = (short)f2bf(a.w);
        v[4] = (short)f2bf(b.x); v[5] = (short)f2bf(b.y);
        v[6] = (short)f2bf(b.z); v[7] = (short)f2bf(b.w);
        *(short8*)(out + (size_t)i * 8) = v;
    }
}

// 3 weight matrices in one launch (blockIdx.y selects)
__global__ void cvt_bf16_3(const float* __restrict__ i0, const float* __restrict__ i1,
                           const float* __restrict__ i2,
                           unsigned short* __restrict__ o0, unsigned short* __restrict__ o1,
                           unsigned short* __restrict__ o2, int n8)
{
    const int w = blockIdx.y;
    const float* in = (w == 0) ? i0 : (w == 1) ? i1 : i2;
    unsigned short* out = (w == 0) ? o0 : (w == 1) ? o1 : o2;
    int i = blockIdx.x * blockDim.x + threadIdx.x;
    if (i < n8) {
        const float4* p = (const float4*)(in + (size_t)i * 8);
        float4 a = p[0], b = p[1];
        short8 v;
        v[0] = (short)f2bf(a.x); v[1] = (short)f2bf(a.y);
        v[2] = (short)f2bf(a.z); v[3] = (short)f2bf(a.w);
        v[4] = (short)f2bf(b.x); v[5] = (short)f2bf(b.y);
        v[6] = (short)f2bf(b.z); v[7] = (short)f2bf(b.w);
        *(short8*)(out + (size_t)i * 8) = v;
    }
}

// pack mask int32 -> bits (16 ints -> u16)
__global__ void mask_pack(const int* __restrict__ m, unsigned short* __restrict__ o, int n16)
{
    int i = blockIdx.x * blockDim.x + threadIdx.x;
    if (i < n16) {
        const int4* p = (const int4*)(m + (size_t)i * 16);
        unsigned int bits = 0;
#pragma unroll
        for (int j = 0; j < 4; j++) {
            int4 v = p[j];
            bits |= (v.x != 0 ? 1u : 0u) << (j * 4 + 0);
            bits |= (v.y != 0 ? 1u : 0u) << (j * 4 + 1);
            bits |= (v.z != 0 ? 1u : 0u) << (j * 4 + 2);
            bits |= (v.w != 0 ? 1u : 0u) << (j * 4 + 3);
        }
        o[i] = (unsigned short)bits;
    }
}

// C = A[M,K] @ W[N,K]^T + bias[N]; A,W bf16; bias f32; MFMA bf16, acc fp32
// mode 0: out bf16 [b][h][s][d]; mode 1: out bf16 [b][h][d][s]; mode 2: out f32 [m][n]
__global__ __launch_bounds__(256, 2)
void gemm_bt(const unsigned short* __restrict__ A,
             const unsigned short* __restrict__ W,
             const float* __restrict__ bias,
             void* __restrict__ outv,
             int M, int N, int K, int mode)
{
    __shared__ __align__(16) unsigned short As[128 * 64]; // LDS[row][slot]=glob[row][slot^(row&7)]
    __shared__ __align__(16) unsigned short Bs[128 * 64];
    const int t = threadIdx.x, lane = t & 63, wv = t >> 6;
    const int quad = lane >> 4, l16 = lane & 15;
    const int m0 = blockIdx.x * 128, n0 = blockIdx.y * 128;
    const int wm = (wv >> 1) * 64, wn = (wv & 1) * 64;

    floatx4 acc[4][4] = {};

    for (int k0 = 0; k0 < K; k0 += 64) {
#pragma unroll
        for (int s = 0; s < 4; s++) {
            int e = t + s * 256;
            int row = e >> 3, slot = e & 7;
            int chunk = slot ^ (row & 7);
            gl_lds16(&A[(size_t)(m0 + row) * K + k0 + chunk * 8], &As[wv * 512 + s * 2048]);
            gl_lds16(&W[(size_t)(n0 + row) * K + k0 + chunk * 8], &Bs[wv * 512 + s * 2048]);
        }
        asm volatile("s_waitcnt vmcnt(0)" ::: "memory");
        __syncthreads();

        short8 af[4][2], bfr[4][2];
#pragma unroll
        for (int i = 0; i < 4; i++)
#pragma unroll
            for (int c = 0; c < 2; c++)
                af[i][c] = *(const short8*)&As[(wm + i * 16 + l16) * 64 + (((c * 4 + quad) ^ (l16 & 7)) * 8)];
#pragma unroll
        for (int j = 0; j < 4; j++)
#pragma unroll
            for (int c = 0; c < 2; c++)
                bfr[j][c] = *(const short8*)&Bs[(wn + j * 16 + l16) * 64 + (((c * 4 + quad) ^ (l16 & 7)) * 8)];

#pragma unroll
        for (int c = 0; c < 2; c++)
#pragma unroll
            for (int i = 0; i < 4; i++)
#pragma unroll
                for (int j = 0; j < 4; j++)
                    acc[i][j] = __builtin_amdgcn_mfma_f32_16x16x32_bf16(af[i][c], bfr[j][c], acc[i][j], 0, 0, 0);
        __syncthreads();
    }

    // C/D layout: col=lane&15, row=quad*4+reg
#pragma unroll
    for (int i = 0; i < 4; i++) {
#pragma unroll
        for (int j = 0; j < 4; j++) {
            int n = n0 + wn + j * 16 + l16;
            float bv = bias[n];
#pragma unroll
            for (int r = 0; r < 4; r++) {
                int m = m0 + wm + i * 16 + quad * 4 + r;
                float v = acc[i][j][r] + bv;
                if (mode == 2) {
                    ((float*)outv)[(size_t)m * N + n] = v;
                } else {
                    int b = m >> 11, s = m & 2047, h = n >> 6, d = n & 63;
                    size_t idx = (mode == 0)
                        ? (((size_t)b * 16 + h) * 2048 + s) * 64 + d
                        : (((size_t)b * 16 + h) * 64 + d) * 2048 + s;
                    ((unsigned short*)outv)[idx] = f2bf(v);
                }
            }
        }
    }
}

// flash attention, static-max softmax, swapped QK^T (S^T = K·Q^T via 32x32x16 MFMA).
// R4 == R1-proven softmax/denominator structure. R5's ONLY attn delta: exp2f -> ex2
// (raw v_exp_f32 builtin). Ones-MFMA denominator is ABANDONED (R2/R3 failures,
// R4 bisect convicted the softmax-refactor block; Osum was its only remaining member
// once this round exonerates ex2).
__global__ __launch_bounds__(256, 4)
void attn(const unsigned short* __restrict__ qb,
          const unsigned short* __restrict__ kb,
          const unsigned short* __restrict__ vtb,
          const unsigned char* __restrict__ mb,
          unsigned short* __restrict__ ob)
{
    __shared__ __align__(16) unsigned short Ks[2][64 * 64]; // [key][d] swizzled
    __shared__ __align__(16) unsigned short Vs[2][64 * 64]; // [d][key] swizzled
    const int t = threadIdx.x, lane = t & 63, wv = t >> 6;
    const int hi = lane >> 5, l31 = lane & 31;
    const int bh = blockIdx.x & 63;           // same bh -> same XCD (mod-8 invariant)
    const int b = bh >> 4, h = bh & 15;
    const int q0 = (blockIdx.x >> 6) * 128;
    const size_t kvbase = (size_t)bh * 2048 * 64;
    // p = exp(s/8 - 10) = exp2(s*0.125*log2e - 10*log2e)
    const float K1 = 0.1803368801f;           // 0.125 * log2(e)
    const float K2 = -14.4269504089f;         // -10 * log2(e)
    const float PM = 4.5399931e-05f;          // exp(1e-11 - 10)

    const int qr = q0 + wv * 32 + l31;        // this lane's q-row

    // Q as B-fragment: qf[g] = Q[q=l31][d = g*16 + hi*8 + j], j=0..7
    short8 qf[4];
#pragma unroll
    for (int g = 0; g < 4; g++)
        qf[g] = *(const short8*)&qb[kvbase + (size_t)qr * 64 + g * 16 + hi * 8];

    const uint2* mrowp = (const uint2*)(mb + ((size_t)b * 2048 + qr) * 256);
    uint2 mcur = mrowp[0];

    floatx16 O[2] = {};   // O^T tiles (dtile 0: d 0..31, dtile 1: d 32..63); C layout col=q
    float lrun = 0.f;

    // prologue: stage tile 0 into buffer 0
#pragma unroll
    for (int s = 0; s < 2; s++) {
        int e = t + s * 256;
        int row = e >> 3, slot = e & 7, chunk = slot ^ (row & 7);
        gl_lds16(&kb[kvbase + (size_t)row * 64 + chunk * 8], &Ks[0][wv * 512 + s * 2048]);
        gl_lds16(&vtb[kvbase + (size_t)row * 2048 + chunk * 8], &Vs[0][wv * 512 + s * 2048]);
    }

    for (int kt = 0; kt < 2048; kt += 64) {
        const int cur = (kt >> 6) & 1;
        asm volatile("s_waitcnt vmcnt(0)" ::: "memory"); // my stage loads for cur landed
        __syncthreads();                                 // everyone's landed; prev reads done

        // issue next tile's stage + mask load; they fly across this tile's compute
        uint2 mnext = mcur;
        if (kt + 64 < 2048) {
#pragma unroll
            for (int s = 0; s < 2; s++) {
                int e = t + s * 256;
                int row = e >> 3, slot = e & 7, chunk = slot ^ (row & 7);
                gl_lds16(&kb[kvbase + (size_t)(kt + 64 + row) * 64 + chunk * 8],
                         &Ks[cur ^ 1][wv * 512 + s * 2048]);
                gl_lds16(&vtb[kvbase + (size_t)row * 2048 + (kt + 64) + chunk * 8],
                         &Vs[cur ^ 1][wv * 512 + s * 2048]);
            }
            mnext = mrowp[(kt >> 6) + 1];
        }

#pragma unroll
        for (int c32 = 0; c32 < 2; c32++) {
            // K as A-fragment: rows c32*32 + l31 of the 64-key tile
            const int krow = c32 * 32 + l31;
            short8 kf[4];
#pragma unroll
            for (int g = 0; g < 4; g++)
                kf[g] = *(const short8*)&Ks[cur][krow * 64 + (((g * 2 + hi) ^ (krow & 7)) * 8)];

            floatx16 C = {};   // S^T: C[row=key][col=q]
#pragma unroll
            for (int g = 0; g < 4; g++)
                C = __builtin_amdgcn_mfma_f32_32x32x16_bf16(kf[g], qf[g], C, 0, 0, 0);

            // softmax (static max), mask select; key(r) = (r&3) + 8*(r>>2) + 4*hi
            unsigned int w = (c32 ? mcur.y : mcur.x) >> (hi * 4);
            float p[16];
            float rs = 0.f;
#pragma unroll
            for (int r = 0; r < 16; r++) {
                float e_ = ex2(fmaf(C[r], K1, K2));   // R5 delta: raw v_exp_f32
                unsigned int bit = (w >> ((r & 3) + 8 * (r >> 2))) & 1u;
                p[r] = bit ? e_ : PM;
                rs += p[r];
            }
            lrun += rs;

            // P -> bf16 PV B-frags: 8 cvt_pk + 4 permlane32_swap
            unsigned int s_[8];
#pragma unroll
            for (int i = 0; i < 8; i++) s_[i] = pk_bf16(p[2 * i], p[2 * i + 1]);
            plane_swap(s_[0], s_[2]); plane_swap(s_[1], s_[3]);
            plane_swap(s_[4], s_[6]); plane_swap(s_[5], s_[7]);
            short8 fragA = __builtin_bit_cast(short8, (uintx4){s_[0], s_[1], s_[2], s_[3]}); // keys c32*32+0..15
            short8 fragB = __builtin_bit_cast(short8, (uintx4){s_[4], s_[5], s_[6], s_[7]}); // keys c32*32+16..31

            // O^T[dtile] += V^T-frag · P-frag
#pragma unroll
            for (int dt = 0; dt < 2; dt++) {
                const int vrow = dt * 32 + l31;
                short8 vA = *(const short8*)&Vs[cur][vrow * 64 + (((c32 * 4 + hi) ^ (vrow & 7)) * 8)];
                short8 vB = *(const short8*)&Vs[cur][vrow * 64 + (((c32 * 4 + 2 + hi) ^ (vrow & 7)) * 8)];
                O[dt] = __builtin_amdgcn_mfma_f32_32x32x16_bf16(vA, fragA, O[dt], 0, 0, 0);
                O[dt] = __builtin_amdgcn_mfma_f32_32x32x16_bf16(vB, fragB, O[dt], 0, 0, 0);
            }
        }
        mcur = mnext;
        __syncthreads(); // all reads of cur done before next iter overwrites cur^1
    }

    // epilogue: combine the two key-half partial sums (same q in lane and lane^32)
    float l = lrun + __shfl_xor(lrun, 32, 64);
    float inv = 1.0f / l;
#pragma unroll
    for (int dt = 0; dt < 2; dt++)
#pragma unroll
        for (int g = 0; g < 4; g++) {
            int d0 = dt * 32 + 8 * g + 4 * hi;          // rows d = d0..d0+3 for regs 4g..4g+3
            unsigned int w0 = pk_bf16(O[dt][4 * g + 0] * inv, O[dt][4 * g + 1] * inv);
            unsigned int w1 = pk_bf16(O[dt][4 * g + 2] * inv, O[dt][4 * g + 3] * inv);
            uint2 ww; ww.x = w0; ww.y = w1;
            *(uint2*)&ob[((size_t)b * 2048 + qr) * 1024 + h * 64 + d0] = ww;
        }
}

extern "C" void kernel_launch(void* const* d_in, const int* in_sizes, int n_in,
                              void* d_out, int out_size, void* d_ws, size_t ws_size,
                              hipStream_t stream)
{
    const float* query = (const float*)d_in[0];
    const float* key   = (const float*)d_in[1];
    const float* value = (const float*)d_in[2];
    const int*   mask  = (const int*)d_in[3];
    const float* wq = (const float*)d_in[4];
    const float* bq = (const float*)d_in[5];
    const float* wk = (const float*)d_in[6];
    const float* bk = (const float*)d_in[7];
    const float* wv = (const float*)d_in[8];
    const float* bv = (const float*)d_in[9];
    const float* wo = (const float*)d_in[10];
    const float* bo = (const float*)d_in[11];

    // ws (48 MB): S0 | S1 | S2, 16 MB each.
    // d_out (32 MB f32): D0 = vtb bf16 [0,16) | WQ [16,18) | WK [18,20) | WV [20,22) | MB mask [22,24).
    // All d_out scratch is dead before the final gemm overwrites d_out with f32 output.
    // wo cannot live in d_out (final gemm reads it while writing d_out) -> S1 post-attn.
    char* ws = (char*)d_ws;
    const size_t T = 16777216;
    unsigned short* S0 = (unsigned short*)(ws);
    unsigned short* S1 = (unsigned short*)(ws + T);
    unsigned short* S2 = (unsigned short*)(ws + 2 * T);
    unsigned short* D0 = (unsigned short*)d_out;
    unsigned short* WQ = (unsigned short*)((char*)d_out + T);
    unsigned short* WK = (unsigned short*)((char*)d_out + T + 2097152);
    unsigned short* WV = (unsigned short*)((char*)d_out + T + 2 * 2097152);
    unsigned short* MB = (unsigned short*)((char*)d_out + T + 3 * 2097152);

    dim3 g(64, 8); // M/128, N/128

    // weights (q,k,v) in one launch; mask pack
    cvt_bf16_3<<<dim3(512, 3), 256, 0, stream>>>(wq, wk, wv, WQ, WK, WV, 131072);
    mask_pack<<<dim3(4096), 256, 0, stream>>>(mask, MB, 1048576);

    // Q = query @ wq^T + bq
    cvt_bf16<<<dim3(4096), 256, 0, stream>>>(query, S0, 1048576);
    gemm_bt<<<g, 256, 0, stream>>>(S0, WQ, bq, S1, 8192, 1024, 1024, 0);
    // K
    cvt_bf16<<<dim3(4096), 256, 0, stream>>>(key, S0, 1048576);
    gemm_bt<<<g, 256, 0, stream>>>(S0, WK, bk, S2, 8192, 1024, 1024, 0);
    // V (transposed layout)
    cvt_bf16<<<dim3(4096), 256, 0, stream>>>(value, S0, 1048576);
    gemm_bt<<<g, 256, 0, stream>>>(S0, WV, bv, D0, 8192, 1024, 1024, 1);

    attn<<<dim3(1024), 256, 0, stream>>>(S1, S2, D0, (const unsigned char*)MB, S0);

    // out = ob @ wo^T + bo  (f32 output)
    cvt_bf16<<<dim3(512), 256, 0, stream>>>(wo, S1, 131072);
    gemm_bt<<<g, 256, 0, stream>>>(S0, S1, bo, d_out, 8192, 1024, 1024, 2);
}